// Round 1
// baseline (604.559 us; speedup 1.0000x reference)
//
#include <hip/hip_runtime.h>
#include <cmath>

#define FILT 11
#define RAD 5
#define OT 32                 // output tile (OT x OT)
#define IT (OT + FILT - 1)    // input tile 42

struct GW { float w[FILT]; };

// ---- order-preserving float<->uint encode for atomic min/max ----
__device__ __forceinline__ unsigned enc_f(float f) {
    unsigned u = __float_as_uint(f);
    return (u & 0x80000000u) ? ~u : (u | 0x80000000u);
}
__device__ __forceinline__ float dec_f(unsigned u) {
    return (u & 0x80000000u) ? __uint_as_float(u & 0x7FFFFFFFu)
                             : __uint_as_float(~u);
}

__global__ void init_acc(unsigned* ws) {
    int t = threadIdx.x;
    if (t == 0) { ws[0] = 0u; ws[1] = 0xFFFFFFFFu; }
    for (int i = 2 + t; i < 512; i += blockDim.x) ws[i] = 0u;  // float 0.0
}

__global__ void minmax_kernel(const float4* __restrict__ t, long n4, unsigned* mm) {
    unsigned mx = 0u, mn = 0xFFFFFFFFu;
    long stride = (long)gridDim.x * blockDim.x;
    for (long i = (long)blockIdx.x * blockDim.x + threadIdx.x; i < n4; i += stride) {
        float4 v = t[i];
        unsigned a = enc_f(v.x), b = enc_f(v.y), c = enc_f(v.z), d = enc_f(v.w);
        mx = max(mx, max(max(a, b), max(c, d)));
        mn = min(mn, min(min(a, b), min(c, d)));
    }
    for (int off = 32; off; off >>= 1) {
        mx = max(mx, (unsigned)__shfl_down((int)mx, off));
        mn = min(mn, (unsigned)__shfl_down((int)mn, off));
    }
    __shared__ unsigned smx[4], smn[4];
    int wid = threadIdx.x >> 6, lane = threadIdx.x & 63;
    if (lane == 0) { smx[wid] = mx; smn[wid] = mn; }
    __syncthreads();
    if (threadIdx.x == 0) {
        for (int i = 1; i < 4; i++) { mx = max(mx, smx[i]); mn = min(mn, smn[i]); }
        atomicMax(&mm[0], mx);
        atomicMin(&mm[1], mn);
    }
}

__global__ __launch_bounds__(256) void ssim_kernel(
    const float* __restrict__ x, const float* __restrict__ y,
    int H, int W, int Ho, int Wo, int C,
    const unsigned* __restrict__ mm,
    float* __restrict__ cs_sum, float* __restrict__ ssim_sum, GW gw)
{
    __shared__ float sx[IT][IT + 1];
    __shared__ float sy[IT][IT + 1];
    __shared__ float hb[5][IT][OT + 1];

    const int img = blockIdx.z;       // n*C + c
    const int n = img / C;
    const int oy0 = blockIdx.y * OT;
    const int ox0 = blockIdx.x * OT;
    const float* xp = x + (size_t)img * H * W;
    const float* yp = y + (size_t)img * H * W;

    for (int i = threadIdx.x; i < IT * IT; i += 256) {
        int r = i / IT, c = i % IT;
        int gr = min(oy0 + r, H - 1);
        int gc = min(ox0 + c, W - 1);
        size_t gidx = (size_t)gr * W + gc;
        sx[r][c] = xp[gidx];
        sy[r][c] = yp[gidx];
    }
    __syncthreads();

    // horizontal pass: 5 blurred quantities, IT rows x OT cols
    for (int i = threadIdx.x; i < IT * OT; i += 256) {
        int r = i / OT, c = i % OT;
        float hx = 0.f, hy = 0.f, hxx = 0.f, hyy = 0.f, hxy = 0.f;
#pragma unroll
        for (int k = 0; k < FILT; k++) {
            float w = gw.w[k];
            float xv = sx[r][c + k];
            float yv = sy[r][c + k];
            hx += w * xv;
            hy += w * yv;
            hxx += w * xv * xv;
            hyy += w * yv * yv;
            hxy += w * xv * yv;
        }
        hb[0][r][c] = hx;
        hb[1][r][c] = hy;
        hb[2][r][c] = hxx;
        hb[3][r][c] = hyy;
        hb[4][r][c] = hxy;
    }
    __syncthreads();

    float mv = dec_f(mm[0]) - dec_f(mm[1]);
    float c1 = (0.01f * mv) * (0.01f * mv);
    float c2 = (0.03f * mv) * (0.03f * mv);

    float lcs = 0.f, lss = 0.f;
    for (int i = threadIdx.x; i < OT * OT; i += 256) {
        int r = i / OT, c = i % OT;
        if (oy0 + r < Ho && ox0 + c < Wo) {
            float m1 = 0.f, m2 = 0.f, mxx = 0.f, myy = 0.f, mxy = 0.f;
#pragma unroll
            for (int k = 0; k < FILT; k++) {
                float w = gw.w[k];
                m1 += w * hb[0][r + k][c];
                m2 += w * hb[1][r + k][c];
                mxx += w * hb[2][r + k][c];
                myy += w * hb[3][r + k][c];
                mxy += w * hb[4][r + k][c];
            }
            float mu1sq = m1 * m1, mu2sq = m2 * m2, mu12 = m1 * m2;
            float s1 = mxx - mu1sq, s2 = myy - mu2sq, s12 = mxy - mu12;
            float cs = (2.f * s12 + c2) / (s1 + s2 + c2);
            float ss = (2.f * mu12 + c1) / (mu1sq + mu2sq + c1) * cs;
            lcs += cs;
            lss += ss;
        }
    }
    for (int off = 32; off; off >>= 1) {
        lcs += __shfl_down(lcs, off);
        lss += __shfl_down(lss, off);
    }
    __shared__ float rcs[4], rss[4];
    int wid = threadIdx.x >> 6, lane = threadIdx.x & 63;
    if (lane == 0) { rcs[wid] = lcs; rss[wid] = lss; }
    __syncthreads();
    if (threadIdx.x == 0) {
        float tcs = rcs[0] + rcs[1] + rcs[2] + rcs[3];
        float tss = rss[0] + rss[1] + rss[2] + rss[3];
        atomicAdd(&cs_sum[n], tcs);
        atomicAdd(&ssim_sum[n], tss);
    }
}

__global__ void pool_kernel(const float* __restrict__ in, float* __restrict__ out,
                            int H, int W, long total)
{
    int Ho = H / 2, Wo = W / 2;
    long stride = (long)gridDim.x * blockDim.x;
    for (long i = (long)blockIdx.x * blockDim.x + threadIdx.x; i < total; i += stride) {
        long wo = i % Wo;
        long t = i / Wo;
        long ho = t % Ho;
        long img = t / Ho;
        const float* p = in + (size_t)img * H * W + (size_t)(2 * ho) * W + 2 * wo;
        out[i] = 0.25f * (p[0] + p[1] + p[W] + p[W + 1]);
    }
}

__global__ void final_kernel(const float* __restrict__ cs_sum,
                             const float* __restrict__ ssim_sum,
                             float* __restrict__ out)
{
    const float cnt[5] = {3.f * 502 * 502, 3.f * 246 * 246, 3.f * 118 * 118,
                          3.f * 54 * 54, 3.f * 22 * 22};
    const float wts[5] = {0.0448f, 0.2856f, 0.3001f, 0.2363f, 0.1333f};
    int n = threadIdx.x;
    float ms = 0.f;
    if (n < 32) {
        float ssim = ssim_sum[4 * 32 + n] / cnt[4];
        float t = powf(ssim, wts[4]);
        ms = 1.f;
        for (int l = 0; l < 4; l++) {
            float cs = cs_sum[l * 32 + n] / cnt[l];
            ms *= powf(cs, wts[l]) * t;   // faithful: ssim^w4 inside the product
        }
    }
    for (int off = 32; off; off >>= 1) ms += __shfl_down(ms, off);
    if (threadIdx.x == 0) out[0] = ms / 32.f;
}

extern "C" void kernel_launch(void* const* d_in, const int* in_sizes, int n_in,
                              void* d_out, int out_size, void* d_ws, size_t ws_size,
                              hipStream_t stream) {
    const float* x0 = (const float*)d_in[0];
    const float* y0 = (const float*)d_in[1];
    float* out = (float*)d_out;
    float* ws = (float*)d_ws;
    unsigned* mm = (unsigned*)d_ws;
    float* cs_sum = ws + 2;
    float* ssim_sum = ws + 2 + 5 * 32;

    const int N = 32, C = 3;
    const int Hs[5] = {512, 256, 128, 64, 32};

    // pyramid buffers in ws (floats), after 512-float accumulator area
    float* wp = ws + 512;
    float* pxw[5] = {nullptr, nullptr, nullptr, nullptr, nullptr};
    float* pyw[5] = {nullptr, nullptr, nullptr, nullptr, nullptr};
    for (int l = 1; l < 5; l++) {
        size_t sz = (size_t)N * C * Hs[l] * Hs[l];
        pxw[l] = wp; wp += sz;
        pyw[l] = wp; wp += sz;
    }
    const float* px[5] = {x0, pxw[1], pxw[2], pxw[3], pxw[4]};
    const float* py[5] = {y0, pyw[1], pyw[2], pyw[3], pyw[4]};

    // gaussian weights (softmax of -c^2/(2*sigma^2)), fp32-faithful enough
    GW gw;
    {
        double tmp[FILT], s = 0.0;
        for (int k = 0; k < FILT; k++) {
            double c = (double)k - (FILT - 1) / 2.0;
            tmp[k] = exp(-c * c / (2.0 * 1.5 * 1.5));
            s += tmp[k];
        }
        for (int k = 0; k < FILT; k++) gw.w[k] = (float)(tmp[k] / s);
    }

    init_acc<<<1, 256, 0, stream>>>(mm);
    long n4 = (long)N * C * 512 * 512 / 4;
    minmax_kernel<<<1024, 256, 0, stream>>>((const float4*)y0, n4, mm);

    for (int l = 0; l < 5; l++) {
        int H = Hs[l], Ho = H - (FILT - 1);
        dim3 grid((Ho + OT - 1) / OT, (Ho + OT - 1) / OT, N * C);
        ssim_kernel<<<grid, 256, 0, stream>>>(px[l], py[l], H, H, Ho, Ho, C, mm,
                                              cs_sum + l * 32, ssim_sum + l * 32, gw);
        if (l < 4) {
            long tot = (long)N * C * (H / 2) * (H / 2);
            long gl = (tot + 255) / 256;
            int g = (int)(gl < 2048 ? gl : 2048);
            pool_kernel<<<g, 256, 0, stream>>>(px[l], pxw[l + 1], H, H, tot);
            pool_kernel<<<g, 256, 0, stream>>>(py[l], pyw[l + 1], H, H, tot);
        }
    }
    final_kernel<<<1, 64, 0, stream>>>(cs_sum, ssim_sum, out);
}